// Round 1
// baseline (260.645 us; speedup 1.0000x reference)
//
#include <hip/hip_runtime.h>
#include <stdint.h>
#include <stddef.h>

#define EPS   1e-5f
#define NB    4
#define CINCH 128
#define CI    64
#define NPIX  4096

typedef __bf16 bf16_t;
typedef bf16_t bf16x8 __attribute__((ext_vector_type(8)));
typedef float  f32x4  __attribute__((ext_vector_type(4)));

__device__ __forceinline__ f32x4 mfma16(bf16x8 a, bf16x8 b, f32x4 c) {
  return __builtin_amdgcn_mfma_f32_16x16x32_bf16(a, b, c, 0, 0, 0);
}
__device__ __forceinline__ f32x4 fzero4() {
  f32x4 z = {0.f, 0.f, 0.f, 0.f};
  return z;
}

// ---------------------------------------------------------------------------
// Workspace layout (bytes):
//   thetaT_h [B][N][64] bf16            off  0 MiB   (2 MiB)
//   thetaT_l [B][N][64] bf16            off  2 MiB
//   phiT_h   [B][N][64] bf16 swizzled   off  4 MiB
//   phiT_l   [B][N][64] bf16 swizzled   off  6 MiB
//   g_cm     [B][64][N] bf16 swizzled   off  8 MiB
//   Opart    [B][N][4][64] f32          off 10 MiB   (16 MiB)
//   ml       [B][N][4][2]  f32          off 26 MiB   (0.5 MiB)
// Swizzle (phi): within each 128-byte key-row, byte = (c*2) ^ ((key&7)<<4)
// Swizzle (g):   within each 128-byte 64-key block of a channel row,
//                byte = ((m&63)*2) ^ ((c&7)<<4)
// Both producer (proj) and consumer (flash LDS reads) use these formulas;
// staging into LDS is a verbatim byte copy, so they stay consistent.
// ---------------------------------------------------------------------------

// ========================= stage 1a: theta + x1 copy ========================
__global__ __launch_bounds__(256) void proj_theta(
    const float* __restrict__ x1,
    const float* __restrict__ w,  const float* __restrict__ bb,
    const float* __restrict__ gm, const float* __restrict__ bt,
    const float* __restrict__ mn, const float* __restrict__ vr,
    bf16_t* __restrict__ thetaT_h, bf16_t* __restrict__ thetaT_l,
    float* __restrict__ out)
{
  __shared__ float wT[CINCH][CI];   // [c][o] folded weights (32 KiB)
  __shared__ float bfold[CI];
  const int tid = threadIdx.x;
  const int b   = blockIdx.y;
  const int n0  = blockIdx.x * 64;

  for (int idx = tid; idx < CI * CINCH; idx += 256) {
    const int o = idx & 63;
    const int c = idx >> 6;
    const float sc = gm[o] * rsqrtf(vr[o] + EPS);
    wT[c][o] = w[o * CINCH + c] * sc;
    if (c == 0) bfold[o] = bb[o] * sc + bt[o] - mn[o] * sc;
  }
  __syncthreads();

  const int n4 = tid & 15;     // owns n = n0 + n4*4 .. +3
  const int og = tid >> 4;     // owns o = og*4 .. +3
  const float* xb = x1 + (size_t)b * CINCH * NPIX + n0 + n4 * 4;

  float acc[4][4];
#pragma unroll
  for (int j = 0; j < 4; ++j)
#pragma unroll
    for (int i = 0; i < 4; ++i) acc[j][i] = 0.f;

  for (int c0 = 0; c0 < CINCH; c0 += 4) {
    f32x4 xv[4];
#pragma unroll
    for (int cc = 0; cc < 4; ++cc)
      xv[cc] = *(const f32x4*)(xb + (size_t)(c0 + cc) * NPIX);
#pragma unroll
    for (int cc = 0; cc < 4; ++cc) {
      const f32x4 wv = *(const f32x4*)&wT[c0 + cc][og * 4];
#pragma unroll
      for (int j = 0; j < 4; ++j)
#pragma unroll
        for (int i = 0; i < 4; ++i)
          acc[j][i] += wv[j] * xv[cc][i];
    }
  }

#pragma unroll
  for (int j = 0; j < 4; ++j) {
    const int o = og * 4 + j;
    const float bias = bfold[o];
#pragma unroll
    for (int i = 0; i < 4; ++i) {
      const int n = n0 + n4 * 4 + i;
      const float v = acc[j][i] + bias;
      const bf16_t h = (bf16_t)v;
      const bf16_t l = (bf16_t)(v - (float)h);
      const size_t base = ((size_t)b * NPIX + n) * CI + o;
      thetaT_h[base] = h;
      thetaT_l[base] = l;
    }
  }

  // concat: out channels [128,256) = x1
  for (int k = tid; k < CINCH * 64; k += 256) {
    const int c = k >> 6, nl = k & 63;
    out[((size_t)b * 256 + 128 + c) * NPIX + n0 + nl] =
        x1[((size_t)b * CINCH + c) * NPIX + n0 + nl];
  }
}

// ========================= stage 1b: phi + g ================================
__global__ __launch_bounds__(256) void proj_phig(
    const float* __restrict__ x2,
    const float* __restrict__ pw,  const float* __restrict__ pb,
    const float* __restrict__ pg,  const float* __restrict__ pbt,
    const float* __restrict__ pm,  const float* __restrict__ pv,
    const float* __restrict__ gw,  const float* __restrict__ gb,
    const float* __restrict__ gg,  const float* __restrict__ gbt,
    const float* __restrict__ gmn, const float* __restrict__ gv,
    bf16_t* __restrict__ phiT_h, bf16_t* __restrict__ phiT_l,
    bf16_t* __restrict__ g_cm)
{
  __shared__ float wT[CINCH][128];  // [c][o]: o 0-63 phi, 64-127 g (64 KiB)
  __shared__ float bfold[128];
  const int tid = threadIdx.x;
  const int b   = blockIdx.y;
  const int n0  = blockIdx.x * 64;

  for (int idx = tid; idx < 128 * CINCH; idx += 256) {
    const int o  = idx & 127;
    const int c  = idx >> 7;
    const int oo = o & 63;
    float sc, wv_, bb_, bt_, mn_;
    if (o < 64) { sc = pg[oo] * rsqrtf(pv[oo] + EPS); wv_ = pw[oo*CINCH+c]; bb_ = pb[oo]; bt_ = pbt[oo]; mn_ = pm[oo]; }
    else        { sc = gg[oo] * rsqrtf(gv[oo] + EPS); wv_ = gw[oo*CINCH+c]; bb_ = gb[oo]; bt_ = gbt[oo]; mn_ = gmn[oo]; }
    wT[c][o] = wv_ * sc;
    if (c == 0) bfold[o] = bb_ * sc + bt_ - mn_ * sc;
  }
  __syncthreads();

  const int n4 = tid & 15;
  const int og = tid >> 4;     // o = og*8 .. +7
  const float* xb = x2 + (size_t)b * CINCH * NPIX + n0 + n4 * 4;

  float acc[8][4];
#pragma unroll
  for (int j = 0; j < 8; ++j)
#pragma unroll
    for (int i = 0; i < 4; ++i) acc[j][i] = 0.f;

  for (int c0 = 0; c0 < CINCH; c0 += 4) {
    f32x4 xv[4];
#pragma unroll
    for (int cc = 0; cc < 4; ++cc)
      xv[cc] = *(const f32x4*)(xb + (size_t)(c0 + cc) * NPIX);
#pragma unroll
    for (int cc = 0; cc < 4; ++cc) {
      const f32x4 wv0 = *(const f32x4*)&wT[c0 + cc][og * 8];
      const f32x4 wv1 = *(const f32x4*)&wT[c0 + cc][og * 8 + 4];
#pragma unroll
      for (int j = 0; j < 4; ++j)
#pragma unroll
        for (int i = 0; i < 4; ++i) {
          acc[j][i]     += wv0[j] * xv[cc][i];
          acc[j + 4][i] += wv1[j] * xv[cc][i];
        }
    }
  }

#pragma unroll
  for (int j = 0; j < 8; ++j) {
    const int o = og * 8 + j;
    const float bias = bfold[o];
#pragma unroll
    for (int i = 0; i < 4; ++i) {
      const int n = n0 + n4 * 4 + i;
      const float v = acc[j][i] + bias;
      if (o < 64) {  // phi: h/l split, swizzled rows of 128B
        const bf16_t h = (bf16_t)v;
        const bf16_t l = (bf16_t)(v - (float)h);
        const size_t rowb = ((size_t)b * NPIX + n) * 128;
        const int byte = (o * 2) ^ ((n & 7) << 4);
        *(bf16_t*)((char*)phiT_h + rowb + byte) = h;
        *(bf16_t*)((char*)phiT_l + rowb + byte) = l;
      } else {       // g: [c][m] rows, swizzled within 128B key-blocks
        const int c = o - 64;
        const size_t base = ((size_t)b * CI + c) * (NPIX * 2);
        const int byte = ((n & ~63) * 2) + (((n & 63) * 2) ^ ((c & 7) << 4));
        *(bf16_t*)((char*)g_cm + base + byte) = (bf16_t)v;
      }
    }
  }
}

// ========================= stage 2: flash attention =========================
// Grid: 512 = B(4) * qtiles(32) * ksplit(4). Block: 256 (4 waves x 32 q).
// Each WG: queries [qt*128, qt*128+128), keys [ks*1024, +1024) in 64-blocks.
__global__ __launch_bounds__(256, 2) void flash_attn(
    const bf16_t* __restrict__ thetaT_h, const bf16_t* __restrict__ thetaT_l,
    const bf16_t* __restrict__ phiT_h,   const bf16_t* __restrict__ phiT_l,
    const bf16_t* __restrict__ g_cm,
    float* __restrict__ Opart, float* __restrict__ mlbuf)
{
  __shared__ __attribute__((aligned(16))) char sPhiH[64 * 128];
  __shared__ __attribute__((aligned(16))) char sPhiL[64 * 128];
  __shared__ __attribute__((aligned(16))) char sV[64 * 128];
  __shared__ __attribute__((aligned(16))) char sP[4][32 * 144];  // per-wave P

  const int tid  = threadIdx.x;
  const int lane = tid & 63;
  const int wid  = tid >> 6;
  const int lrow = lane & 15;
  const int lhi  = lane >> 4;

  const int wg = blockIdx.x;
  const int b  = wg >> 7;
  const int qt = (wg & 127) >> 2;
  const int ks = wg & 3;
  const int q0 = qt * 128 + wid * 32;
  const int m0 = ks * 1024;

  // Q fragments (B operand), h & l splits: [ntile][kchunk]
  bf16x8 qh[2][2], qlv[2][2];
  {
    const bf16_t* qbh = thetaT_h + ((size_t)b * NPIX + q0 + lrow) * CI + lhi * 8;
    const bf16_t* qbl = thetaT_l + ((size_t)b * NPIX + q0 + lrow) * CI + lhi * 8;
#pragma unroll
    for (int nt = 0; nt < 2; ++nt)
#pragma unroll
      for (int kk = 0; kk < 2; ++kk) {
        qh[nt][kk]  = *(const bf16x8*)(qbh + nt * 16 * CI + kk * 32);
        qlv[nt][kk] = *(const bf16x8*)(qbl + nt * 16 * CI + kk * 32);
      }
  }

  f32x4 oacc[2][4];
#pragma unroll
  for (int a = 0; a < 2; ++a)
#pragma unroll
    for (int c = 0; c < 4; ++c) oacc[a][c] = fzero4();

  float m_run[2] = {-1e30f, -1e30f};
  float l_run[2] = {0.f, 0.f};

  char* const Pw = sP[wid];

  for (int kb = 0; kb < 16; ++kb) {
    const int mg = m0 + kb * 64;
    __syncthreads();  // previous iteration's readers done
    // ---- stage K(h/l) and V tiles: verbatim 16B copies ----
    {
      const char* srcPH = (const char*)phiT_h + ((size_t)b * NPIX + mg) * 128;
      const char* srcPL = (const char*)phiT_l + ((size_t)b * NPIX + mg) * 128;
#pragma unroll
      for (int r = 0; r < 6; ++r) {
        const int chunk = r * 256 + tid;   // 0..1535
        if (chunk < 512) {
          *(f32x4*)(sPhiH + chunk * 16) = *(const f32x4*)(srcPH + chunk * 16);
        } else if (chunk < 1024) {
          const int c2 = chunk - 512;
          *(f32x4*)(sPhiL + c2 * 16) = *(const f32x4*)(srcPL + c2 * 16);
        } else {
          const int c2  = chunk - 1024;
          const int row = c2 >> 3;
          const int col = (c2 & 7) * 16;
          *(f32x4*)(sV + row * 128 + col) =
              *(const f32x4*)((const char*)g_cm +
                              ((size_t)b * CI + row) * (NPIX * 2) + mg * 2 + col);
        }
      }
    }
    __syncthreads();

    // ---- S^T = phi * theta^T  ([64 keys] x [32 q]), bf16x3 ----
    f32x4 s[4][2];
#pragma unroll
    for (int mt = 0; mt < 4; ++mt)
#pragma unroll
      for (int nt = 0; nt < 2; ++nt) s[mt][nt] = fzero4();

#pragma unroll
    for (int mt = 0; mt < 4; ++mt) {
      const int row = mt * 16 + lrow;
      const int swz = (row & 7) << 4;
#pragma unroll
      for (int kk = 0; kk < 2; ++kk) {
        const int byte = row * 128 + ((kk * 64 + lhi * 16) ^ swz);
        const bf16x8 aH = *(const bf16x8*)(sPhiH + byte);
        const bf16x8 aL = *(const bf16x8*)(sPhiL + byte);
#pragma unroll
        for (int nt = 0; nt < 2; ++nt) {
          s[mt][nt] = mfma16(aH, qh[nt][kk],  s[mt][nt]);
          s[mt][nt] = mfma16(aH, qlv[nt][kk], s[mt][nt]);
          s[mt][nt] = mfma16(aL, qh[nt][kk],  s[mt][nt]);
        }
      }
    }

    // ---- online softmax: lane owns q-col = nt*16 + lrow ----
    float a2[2];
#pragma unroll
    for (int nt = 0; nt < 2; ++nt) {
      float mx = -1e30f;
#pragma unroll
      for (int mt = 0; mt < 4; ++mt)
#pragma unroll
        for (int r = 0; r < 4; ++r) mx = fmaxf(mx, s[mt][nt][r]);
      mx = fmaxf(mx, __shfl_xor(mx, 16));
      mx = fmaxf(mx, __shfl_xor(mx, 32));
      const float mnew  = fmaxf(m_run[nt], mx);
      const float alpha = __expf(m_run[nt] - mnew);
      float lsum = 0.f;
#pragma unroll
      for (int mt = 0; mt < 4; ++mt)
#pragma unroll
        for (int r = 0; r < 4; ++r) {
          const float p = __expf(s[mt][nt][r] - mnew);
          s[mt][nt][r] = p;
          lsum += p;
        }
      lsum += __shfl_xor(lsum, 16);
      lsum += __shfl_xor(lsum, 32);
      l_run[nt] = l_run[nt] * alpha + lsum;
      m_run[nt] = mnew;
      a2[nt] = alpha;
    }

    // ---- rescale O (broadcast alpha from stats layout to O layout) ----
#pragma unroll
    for (int qt2 = 0; qt2 < 2; ++qt2) {
#pragma unroll
      for (int r = 0; r < 4; ++r) {
        const float av = __shfl(a2[qt2], lhi * 4 + r);
#pragma unroll
        for (int ct = 0; ct < 4; ++ct) oacc[qt2][ct][r] *= av;
      }
    }

    // ---- pack P (bf16) into LDS [32 q][pitch 144B] ----
#pragma unroll
    for (int mt = 0; mt < 4; ++mt)
#pragma unroll
      for (int nt = 0; nt < 2; ++nt) {
        union { bf16_t h[4]; uint32_t u[2]; } pk;
#pragma unroll
        for (int r = 0; r < 4; ++r) pk.h[r] = (bf16_t)s[mt][nt][r];
        const int q    = nt * 16 + lrow;
        const int mloc = mt * 16 + lhi * 4;
        *(uint2*)(Pw + q * 144 + mloc * 2) = make_uint2(pk.u[0], pk.u[1]);
      }

    // ---- PV: O[q][c] += P[q][m] * V[m][c] ----
    bf16x8 bV[2][4];
#pragma unroll
    for (int ct = 0; ct < 4; ++ct) {
      const int row = ct * 16 + lrow;
      const int swz = (row & 7) << 4;
#pragma unroll
      for (int kk = 0; kk < 2; ++kk)
        bV[kk][ct] = *(const bf16x8*)(sV + row * 128 + ((kk * 64 + lhi * 16) ^ swz));
    }
#pragma unroll
    for (int qt2 = 0; qt2 < 2; ++qt2) {
#pragma unroll
      for (int kk = 0; kk < 2; ++kk) {
        const bf16x8 pfrag =
            *(const bf16x8*)(Pw + (qt2 * 16 + lrow) * 144 + kk * 64 + lhi * 16);
#pragma unroll
        for (int ct = 0; ct < 4; ++ct)
          oacc[qt2][ct] = mfma16(pfrag, bV[kk][ct], oacc[qt2][ct]);
      }
    }
  }

  // ---- epilogue: unnormalized partial O + (m, l) ----
#pragma unroll
  for (int qt2 = 0; qt2 < 2; ++qt2)
#pragma unroll
    for (int ct = 0; ct < 4; ++ct)
#pragma unroll
      for (int r = 0; r < 4; ++r) {
        const int q = q0 + qt2 * 16 + lhi * 4 + r;
        const int c = ct * 16 + lrow;
        Opart[(((size_t)b * NPIX + q) * 4 + ks) * 64 + c] = oacc[qt2][ct][r];
      }
  if (lhi < 2) {
    const int q = q0 + lhi * 16 + lrow;
    const size_t base = (((size_t)b * NPIX + q) * 4 + ks) * 2;
    mlbuf[base]     = m_run[lhi];
    mlbuf[base + 1] = l_run[lhi];
  }
}

// ========================= stage 3: merge + wout + BN =======================
__global__ __launch_bounds__(256) void merge_out(
    const float* __restrict__ Opart, const float* __restrict__ mlbuf,
    const float* __restrict__ ww,  const float* __restrict__ wb,
    const float* __restrict__ wg,  const float* __restrict__ wbt,
    const float* __restrict__ wm,  const float* __restrict__ wvv,
    float* __restrict__ out)
{
  __shared__ float wlds[128][64];
  __shared__ float bfold[128];
  const int tid = threadIdx.x;
  const int b   = blockIdx.y;
  const int n0  = blockIdx.x * 64;

  for (int idx = tid; idx < 128 * 64; idx += 256) {
    const int o = idx >> 6, c = idx & 63;
    const float sc = wg[o] * rsqrtf(wvv[o] + EPS);
    wlds[o][c] = ww[o * 64 + c] * sc;
    if (c == 0) bfold[o] = wb[o] * sc + wbt[o] - wm[o] * sc;
  }
  __syncthreads();

  const int ql = tid & 63;
  const int oh = tid >> 6;   // o = oh*32 .. +31
  const int q  = n0 + ql;
  const size_t sb = ((size_t)b * NPIX + q) * 4;

  float mk[4], lk[4];
#pragma unroll
  for (int ks = 0; ks < 4; ++ks) {
    mk[ks] = mlbuf[(sb + ks) * 2];
    lk[ks] = mlbuf[(sb + ks) * 2 + 1];
  }
  const float M = fmaxf(fmaxf(mk[0], mk[1]), fmaxf(mk[2], mk[3]));
  float al[4]; float den = 0.f;
#pragma unroll
  for (int ks = 0; ks < 4; ++ks) { al[ks] = __expf(mk[ks] - M); den += al[ks] * lk[ks]; }
  const float inv = 1.f / den;
#pragma unroll
  for (int ks = 0; ks < 4; ++ks) al[ks] *= inv;

  float acc[32];
#pragma unroll
  for (int j = 0; j < 32; ++j) acc[j] = 0.f;

  for (int c0 = 0; c0 < 64; c0 += 4) {
    f32x4 mrg = {0.f, 0.f, 0.f, 0.f};
#pragma unroll
    for (int ks = 0; ks < 4; ++ks) {
      const f32x4 pv4 = *(const f32x4*)(Opart + (sb + ks) * 64 + c0);
      mrg += pv4 * al[ks];
    }
#pragma unroll
    for (int j = 0; j < 32; ++j) {
      const f32x4 wv4 = *(const f32x4*)&wlds[oh * 32 + j][c0];
      acc[j] += wv4[0] * mrg[0] + wv4[1] * mrg[1] + wv4[2] * mrg[2] + wv4[3] * mrg[3];
    }
  }

#pragma unroll
  for (int j = 0; j < 32; ++j) {
    const int o = oh * 32 + j;
    out[((size_t)b * 256 + o) * NPIX + q] = acc[j] + bfold[o];
  }
}

// ============================== launcher ====================================
extern "C" void kernel_launch(void* const* d_in, const int* in_sizes, int n_in,
                              void* d_out, int out_size, void* d_ws, size_t ws_size,
                              hipStream_t stream) {
  (void)in_sizes; (void)n_in; (void)out_size; (void)ws_size;
  const float* x1  = (const float*)d_in[0];
  const float* x2  = (const float*)d_in[1];
  const float* tw  = (const float*)d_in[2];
  const float* tb  = (const float*)d_in[3];
  const float* tg  = (const float*)d_in[4];
  const float* tbt = (const float*)d_in[5];
  const float* tm  = (const float*)d_in[6];
  const float* tv  = (const float*)d_in[7];
  const float* pw  = (const float*)d_in[8];
  const float* pb  = (const float*)d_in[9];
  const float* pg  = (const float*)d_in[10];
  const float* pbt = (const float*)d_in[11];
  const float* pm  = (const float*)d_in[12];
  const float* pv  = (const float*)d_in[13];
  const float* gw  = (const float*)d_in[14];
  const float* gb  = (const float*)d_in[15];
  const float* gg  = (const float*)d_in[16];
  const float* gbt = (const float*)d_in[17];
  const float* gmn = (const float*)d_in[18];
  const float* gv  = (const float*)d_in[19];
  const float* ww  = (const float*)d_in[20];
  const float* wb  = (const float*)d_in[21];
  const float* wg  = (const float*)d_in[22];
  const float* wbt = (const float*)d_in[23];
  const float* wm  = (const float*)d_in[24];
  const float* wv  = (const float*)d_in[25];

  float* out = (float*)d_out;
  char*  ws  = (char*)d_ws;
  bf16_t* thetaT_h = (bf16_t*)(ws);
  bf16_t* thetaT_l = (bf16_t*)(ws + (size_t)(2)  * 1048576);
  bf16_t* phiT_h   = (bf16_t*)(ws + (size_t)(4)  * 1048576);
  bf16_t* phiT_l   = (bf16_t*)(ws + (size_t)(6)  * 1048576);
  bf16_t* g_cm     = (bf16_t*)(ws + (size_t)(8)  * 1048576);
  float*  Opart    = (float*) (ws + (size_t)(10) * 1048576);
  float*  mlbuf    = (float*) (ws + (size_t)(26) * 1048576);

  dim3 gp(64, 4);
  proj_theta<<<gp, 256, 0, stream>>>(x1, tw, tb, tg, tbt, tm, tv,
                                     thetaT_h, thetaT_l, out);
  proj_phig<<<gp, 256, 0, stream>>>(x2, pw, pb, pg, pbt, pm, pv,
                                    gw, gb, gg, gbt, gmn, gv,
                                    phiT_h, phiT_l, g_cm);
  flash_attn<<<512, 256, 0, stream>>>(thetaT_h, thetaT_l, phiT_h, phiT_l,
                                      g_cm, Opart, mlbuf);
  merge_out<<<gp, 256, 0, stream>>>(Opart, mlbuf, ww, wb, wg, wbt, wm, wv, out);
}

// Round 2
// 238.278 us; speedup vs baseline: 1.0939x; 1.0939x over previous
//
#include <hip/hip_runtime.h>
#include <stdint.h>
#include <stddef.h>

#define EPS   1e-5f
#define CINCH 128
#define CI    64
#define NPIX  4096

typedef __bf16 bf16_t;
typedef bf16_t bf16x8 __attribute__((ext_vector_type(8)));
typedef float  f32x4  __attribute__((ext_vector_type(4)));

typedef __attribute__((address_space(3))) unsigned int lds_u32;
typedef __attribute__((address_space(1))) const unsigned int glb_u32;

__device__ __forceinline__ f32x4 mfma16(bf16x8 a, bf16x8 b, f32x4 c) {
  return __builtin_amdgcn_mfma_f32_16x16x32_bf16(a, b, c, 0, 0, 0);
}
__device__ __forceinline__ f32x4 fzero4() {
  f32x4 z = {0.f, 0.f, 0.f, 0.f};
  return z;
}
__device__ __forceinline__ void gload16(const void* g, void* l) {
  __builtin_amdgcn_global_load_lds((glb_u32*)g, (lds_u32*)l, 16, 0, 0);
}

// ---------------------------------------------------------------------------
// Workspace layout (bytes):
//   thetaT_h [B][N][64] bf16            off  0 MiB
//   thetaT_l [B][N][64] bf16            off  2 MiB
//   phiT_h   [B][N][64] bf16 swizzled   off  4 MiB
//   phiT_l   [B][N][64] bf16 swizzled   off  6 MiB
//   g_cm     [B][64][N] bf16 swizzled   off  8 MiB
//   Opart    [B][N][4][64] f32          off 10 MiB
//   ml       [B][N][4][2]  f32          off 26 MiB
// Swizzle (phi): within each 128B key-row, byte = (c*2) ^ ((key&7)<<4)
// Swizzle (g):   within each 128B 64-key block: ((m&63)*2) ^ ((c&7)<<4)
// ---------------------------------------------------------------------------

// ===================== stage 1a: theta projection + x1 concat ===============
// grid (128, 4): 32 pixels/block. Compute read-optimal, store via LDS transpose.
__global__ __launch_bounds__(256) void proj_theta(
    const float* __restrict__ x1,
    const float* __restrict__ w,  const float* __restrict__ bb,
    const float* __restrict__ gm, const float* __restrict__ bt,
    const float* __restrict__ mn, const float* __restrict__ vr,
    bf16_t* __restrict__ thetaT_h, bf16_t* __restrict__ thetaT_l,
    float* __restrict__ out)
{
  __shared__ float wT[CINCH][CI];     // [c][o] folded (32 KiB)
  __shared__ float bfold[CI];
  __shared__ float tileF[32][68];     // transpose buffer, pitch 68

  const int tid = threadIdx.x;
  const int b   = blockIdx.y;
  const int n0  = blockIdx.x * 32;

  for (int idx = tid; idx < CI * CINCH; idx += 256) {
    const int o = idx & 63, c = idx >> 6;
    const float sc = gm[o] * rsqrtf(vr[o] + EPS);
    wT[c][o] = w[o * CINCH + c] * sc;
    if (c == 0) bfold[o] = bb[o] * sc + bt[o] - mn[o] * sc;
  }
  __syncthreads();

  const int px = tid & 31;    // pixel n0+px
  const int og = tid >> 5;    // channels og*8..+7
  const float* xb = x1 + (size_t)b * CINCH * NPIX + n0 + px;

  float acc[8];
#pragma unroll
  for (int j = 0; j < 8; ++j) acc[j] = 0.f;

#pragma unroll 4
  for (int c0 = 0; c0 < CINCH; c0 += 4) {
    float xv[4];
#pragma unroll
    for (int cc = 0; cc < 4; ++cc) xv[cc] = xb[(size_t)(c0 + cc) * NPIX];
#pragma unroll
    for (int cc = 0; cc < 4; ++cc) {
      const f32x4 w0 = *(const f32x4*)&wT[c0 + cc][og * 8];
      const f32x4 w1 = *(const f32x4*)&wT[c0 + cc][og * 8 + 4];
#pragma unroll
      for (int j = 0; j < 4; ++j) {
        acc[j]     += w0[j] * xv[cc];
        acc[j + 4] += w1[j] * xv[cc];
      }
    }
  }
#pragma unroll
  for (int j = 0; j < 8; ++j) tileF[px][og * 8 + j] = acc[j] + bfold[og * 8 + j];
  __syncthreads();

  {  // store-optimal: 8 lanes cover one 128B row
    const int px2 = tid >> 3, ogs = tid & 7;
    bf16x8 hv, lv;
#pragma unroll
    for (int j = 0; j < 8; ++j) {
      const float v = tileF[px2][ogs * 8 + j];
      const bf16_t h = (bf16_t)v;
      hv[j] = h;
      lv[j] = (bf16_t)(v - (float)h);
    }
    const size_t base = ((size_t)b * NPIX + n0 + px2) * CI + ogs * 8;
    *(bf16x8*)(thetaT_h + base) = hv;
    *(bf16x8*)(thetaT_l + base) = lv;
  }

  // concat: out channels [128,256) = x1 (vectorized)
#pragma unroll
  for (int i = 0; i < 4; ++i) {
    const int idx = i * 256 + tid;
    const int c = idx >> 3, n4 = (idx & 7) * 4;
    *(f32x4*)(out + ((size_t)b * 256 + 128 + c) * NPIX + n0 + n4) =
        *(const f32x4*)(x1 + ((size_t)b * CINCH + c) * NPIX + n0 + n4);
  }
}

// ===================== stage 1b: phi projection (swizzled h/l) ==============
__global__ __launch_bounds__(256) void proj_phi(
    const float* __restrict__ x2,
    const float* __restrict__ w,  const float* __restrict__ bb,
    const float* __restrict__ gm, const float* __restrict__ bt,
    const float* __restrict__ mn, const float* __restrict__ vr,
    bf16_t* __restrict__ phiT_h, bf16_t* __restrict__ phiT_l)
{
  __shared__ float wT[CINCH][CI];
  __shared__ float bfold[CI];
  __shared__ float tileF[32][68];

  const int tid = threadIdx.x;
  const int b   = blockIdx.y;
  const int n0  = blockIdx.x * 32;

  for (int idx = tid; idx < CI * CINCH; idx += 256) {
    const int o = idx & 63, c = idx >> 6;
    const float sc = gm[o] * rsqrtf(vr[o] + EPS);
    wT[c][o] = w[o * CINCH + c] * sc;
    if (c == 0) bfold[o] = bb[o] * sc + bt[o] - mn[o] * sc;
  }
  __syncthreads();

  const int px = tid & 31;
  const int og = tid >> 5;
  const float* xb = x2 + (size_t)b * CINCH * NPIX + n0 + px;

  float acc[8];
#pragma unroll
  for (int j = 0; j < 8; ++j) acc[j] = 0.f;

#pragma unroll 4
  for (int c0 = 0; c0 < CINCH; c0 += 4) {
    float xv[4];
#pragma unroll
    for (int cc = 0; cc < 4; ++cc) xv[cc] = xb[(size_t)(c0 + cc) * NPIX];
#pragma unroll
    for (int cc = 0; cc < 4; ++cc) {
      const f32x4 w0 = *(const f32x4*)&wT[c0 + cc][og * 8];
      const f32x4 w1 = *(const f32x4*)&wT[c0 + cc][og * 8 + 4];
#pragma unroll
      for (int j = 0; j < 4; ++j) {
        acc[j]     += w0[j] * xv[cc];
        acc[j + 4] += w1[j] * xv[cc];
      }
    }
  }
#pragma unroll
  for (int j = 0; j < 8; ++j) tileF[px][og * 8 + j] = acc[j] + bfold[og * 8 + j];
  __syncthreads();

  {
    const int px2 = tid >> 3, ogs = tid & 7;
    const int n = n0 + px2;
    bf16x8 hv, lv;
#pragma unroll
    for (int j = 0; j < 8; ++j) {
      const float v = tileF[px2][ogs * 8 + j];
      const bf16_t h = (bf16_t)v;
      hv[j] = h;
      lv[j] = (bf16_t)(v - (float)h);
    }
    const size_t rowb = ((size_t)b * NPIX + n) * 128;
    const int byte = (ogs * 16) ^ ((n & 7) << 4);
    *(bf16x8*)((char*)phiT_h + rowb + byte) = hv;
    *(bf16x8*)((char*)phiT_l + rowb + byte) = lv;
  }
}

// ===================== stage 1c: g projection ([c][m] swizzled) =============
__global__ __launch_bounds__(256) void proj_g(
    const float* __restrict__ x2,
    const float* __restrict__ w,  const float* __restrict__ bb,
    const float* __restrict__ gm, const float* __restrict__ bt,
    const float* __restrict__ mn, const float* __restrict__ vr,
    bf16_t* __restrict__ g_cm)
{
  __shared__ float wT[CINCH][CI];
  __shared__ float bfold[CI];
  __shared__ float gT[CI][33];   // [c][m] transpose buffer

  const int tid = threadIdx.x;
  const int b   = blockIdx.y;
  const int n0  = blockIdx.x * 32;

  for (int idx = tid; idx < CI * CINCH; idx += 256) {
    const int o = idx & 63, c = idx >> 6;
    const float sc = gm[o] * rsqrtf(vr[o] + EPS);
    wT[c][o] = w[o * CINCH + c] * sc;
    if (c == 0) bfold[o] = bb[o] * sc + bt[o] - mn[o] * sc;
  }
  __syncthreads();

  const int px = tid & 31;
  const int og = tid >> 5;
  const float* xb = x2 + (size_t)b * CINCH * NPIX + n0 + px;

  float acc[8];
#pragma unroll
  for (int j = 0; j < 8; ++j) acc[j] = 0.f;

#pragma unroll 4
  for (int c0 = 0; c0 < CINCH; c0 += 4) {
    float xv[4];
#pragma unroll
    for (int cc = 0; cc < 4; ++cc) xv[cc] = xb[(size_t)(c0 + cc) * NPIX];
#pragma unroll
    for (int cc = 0; cc < 4; ++cc) {
      const f32x4 w0 = *(const f32x4*)&wT[c0 + cc][og * 8];
      const f32x4 w1 = *(const f32x4*)&wT[c0 + cc][og * 8 + 4];
#pragma unroll
      for (int j = 0; j < 4; ++j) {
        acc[j]     += w0[j] * xv[cc];
        acc[j + 4] += w1[j] * xv[cc];
      }
    }
  }
#pragma unroll
  for (int j = 0; j < 8; ++j) gT[og * 8 + j][px] = acc[j] + bfold[og * 8 + j];
  __syncthreads();

  {  // store: thread owns channel c, 8 consecutive keys -> one swizzled 16B chunk
    const int c  = tid & 63;
    const int mgp = tid >> 6;           // 4 groups of 8 keys
    bf16x8 gv;
#pragma unroll
    for (int j = 0; j < 8; ++j) gv[j] = (bf16_t)gT[c][mgp * 8 + j];
    const int m = n0 + mgp * 8;
    char* rowc = (char*)g_cm + ((size_t)b * CI + c) * (NPIX * 2);
    const int byte = ((m & ~63) * 2) + ((((m & 63) * 2) ^ ((c & 7) << 4)));
    *(bf16x8*)(rowc + byte) = gv;
  }
}

// ========================= stage 2: flash attention =========================
// Grid: 512 = B(4) * qtiles(32) * ksplit(4). Block: 256 (4 waves x 32 q).
// Double-buffered K/V staging via global_load_lds; 1 barrier per K-tile.
__global__ __launch_bounds__(256, 2) void flash_attn(
    const bf16_t* __restrict__ thetaT_h, const bf16_t* __restrict__ thetaT_l,
    const bf16_t* __restrict__ phiT_h,   const bf16_t* __restrict__ phiT_l,
    const bf16_t* __restrict__ g_cm,
    float* __restrict__ Opart, float* __restrict__ mlbuf)
{
  // per buffer: [0,8192)=phiH, [8192,16384)=phiL, [16384,24576)=V
  __shared__ __attribute__((aligned(16))) char sTile[2][24576];
  __shared__ __attribute__((aligned(16))) char sP[4][32 * 144];

  const int tid  = threadIdx.x;
  const int lane = tid & 63;
  const int wid  = tid >> 6;
  const int lrow = lane & 15;
  const int lhi  = lane >> 4;

  const int wg = blockIdx.x;
  const int b  = wg >> 7;
  const int qt = (wg & 127) >> 2;
  const int ks = wg & 3;
  const int q0 = qt * 128 + wid * 32;
  const int m0 = ks * 1024;

  const char* const srcPHb = (const char*)phiT_h + ((size_t)b * NPIX) * 128;
  const char* const srcPLb = (const char*)phiT_l + ((size_t)b * NPIX) * 128;
  const char* const srcVb  = (const char*)g_cm + (size_t)b * CI * (NPIX * 2);

  // async stage of one 64-key tile (24 KiB) into sTile[buf]
  auto stage = [&](int buf, int kb) {
    const int mg = m0 + kb * 64;
    const char* srcPH = srcPHb + (size_t)mg * 128;
    const char* srcPL = srcPLb + (size_t)mg * 128;
    const char* srcV  = srcVb + (size_t)mg * 2;
    char* const dst = sTile[buf];
    int c;
    c = tid;       gload16(srcPH + c * 16, dst + c * 16);
    c = 256 + tid; gload16(srcPH + c * 16, dst + c * 16);
    c = tid;       gload16(srcPL + c * 16, dst + 8192 + c * 16);
    c = 256 + tid; gload16(srcPL + c * 16, dst + 8192 + c * 16);
    c = tid;       gload16(srcV + (size_t)(c >> 3) * (NPIX * 2) + (c & 7) * 16,
                           dst + 16384 + c * 16);
    c = 256 + tid; gload16(srcV + (size_t)(c >> 3) * (NPIX * 2) + (c & 7) * 16,
                           dst + 16384 + c * 16);
  };

  // Q fragments (B operand), h & l splits: [ntile][kchunk]
  bf16x8 qh[2][2], qlv[2][2];
  {
    const bf16_t* qbh = thetaT_h + ((size_t)b * NPIX + q0 + lrow) * CI + lhi * 8;
    const bf16_t* qbl = thetaT_l + ((size_t)b * NPIX + q0 + lrow) * CI + lhi * 8;
#pragma unroll
    for (int nt = 0; nt < 2; ++nt)
#pragma unroll
      for (int kk = 0; kk < 2; ++kk) {
        qh[nt][kk]  = *(const bf16x8*)(qbh + nt * 16 * CI + kk * 32);
        qlv[nt][kk] = *(const bf16x8*)(qbl + nt * 16 * CI + kk * 32);
      }
  }

  f32x4 oacc[2][4];
#pragma unroll
  for (int a = 0; a < 2; ++a)
#pragma unroll
    for (int c = 0; c < 4; ++c) oacc[a][c] = fzero4();

  float m_run[2] = {-1e30f, -1e30f};
  float l_run[2] = {0.f, 0.f};

  char* const Pw = sP[wid];

  stage(0, 0);
  __syncthreads();   // drains vmcnt(0) before barrier => buf0 visible

  for (int kb = 0; kb < 16; ++kb) {
    const int cur = kb & 1;
    if (kb < 15) stage(cur ^ 1, kb + 1);   // async prefetch next tile

    const char* const sPhiH = sTile[cur];
    const char* const sPhiL = sTile[cur] + 8192;
    const char* const sV    = sTile[cur] + 16384;

    // ---- S^T = phi * theta^T  ([64 keys] x [32 q]), bf16x3 ----
    f32x4 s[4][2];
#pragma unroll
    for (int mt = 0; mt < 4; ++mt)
#pragma unroll
      for (int nt = 0; nt < 2; ++nt) s[mt][nt] = fzero4();

#pragma unroll
    for (int mt = 0; mt < 4; ++mt) {
      const int row = mt * 16 + lrow;
      const int swz = (row & 7) << 4;
#pragma unroll
      for (int kk = 0; kk < 2; ++kk) {
        const int byte = row * 128 + ((kk * 64 + lhi * 16) ^ swz);
        const bf16x8 aH = *(const bf16x8*)(sPhiH + byte);
        const bf16x8 aL = *(const bf16x8*)(sPhiL + byte);
#pragma unroll
        for (int nt = 0; nt < 2; ++nt) {
          s[mt][nt] = mfma16(aH, qh[nt][kk],  s[mt][nt]);
          s[mt][nt] = mfma16(aH, qlv[nt][kk], s[mt][nt]);
          s[mt][nt] = mfma16(aL, qh[nt][kk],  s[mt][nt]);
        }
      }
    }

    // ---- online softmax: lane owns q-col = nt*16 + lrow ----
    float a2[2];
#pragma unroll
    for (int nt = 0; nt < 2; ++nt) {
      float mx = -1e30f;
#pragma unroll
      for (int mt = 0; mt < 4; ++mt)
#pragma unroll
        for (int r = 0; r < 4; ++r) mx = fmaxf(mx, s[mt][nt][r]);
      mx = fmaxf(mx, __shfl_xor(mx, 16));
      mx = fmaxf(mx, __shfl_xor(mx, 32));
      const float mnew  = fmaxf(m_run[nt], mx);
      const float alpha = __expf(m_run[nt] - mnew);
      float lsum = 0.f;
#pragma unroll
      for (int mt = 0; mt < 4; ++mt)
#pragma unroll
        for (int r = 0; r < 4; ++r) {
          const float p = __expf(s[mt][nt][r] - mnew);
          s[mt][nt][r] = p;
          lsum += p;
        }
      lsum += __shfl_xor(lsum, 16);
      lsum += __shfl_xor(lsum, 32);
      l_run[nt] = l_run[nt] * alpha + lsum;
      m_run[nt] = mnew;
      a2[nt] = alpha;
    }

    // ---- rescale O ----
#pragma unroll
    for (int qt2 = 0; qt2 < 2; ++qt2) {
#pragma unroll
      for (int r = 0; r < 4; ++r) {
        const float av = __shfl(a2[qt2], lhi * 4 + r);
#pragma unroll
        for (int ct = 0; ct < 4; ++ct) oacc[qt2][ct][r] *= av;
      }
    }

    // ---- pack P (bf16) into LDS [32 q][pitch 144B] ----
#pragma unroll
    for (int mt = 0; mt < 4; ++mt)
#pragma unroll
      for (int nt = 0; nt < 2; ++nt) {
        union { bf16_t h[4]; uint32_t u[2]; } pk;
#pragma unroll
        for (int r = 0; r < 4; ++r) pk.h[r] = (bf16_t)s[mt][nt][r];
        const int q    = nt * 16 + lrow;
        const int mloc = mt * 16 + lhi * 4;
        *(uint2*)(Pw + q * 144 + mloc * 2) = make_uint2(pk.u[0], pk.u[1]);
      }

    // ---- PV: O[q][c] += P[q][m] * V[m][c] ----
    bf16x8 bV[2][4];
#pragma unroll
    for (int ct = 0; ct < 4; ++ct) {
      const int row = ct * 16 + lrow;
      const int swz = (row & 7) << 4;
#pragma unroll
      for (int kk = 0; kk < 2; ++kk)
        bV[kk][ct] = *(const bf16x8*)(sV + row * 128 + ((kk * 64 + lhi * 16) ^ swz));
    }
#pragma unroll
    for (int qt2 = 0; qt2 < 2; ++qt2) {
#pragma unroll
      for (int kk = 0; kk < 2; ++kk) {
        const bf16x8 pfrag =
            *(const bf16x8*)(Pw + (qt2 * 16 + lrow) * 144 + kk * 64 + lhi * 16);
#pragma unroll
        for (int ct = 0; ct < 4; ++ct)
          oacc[qt2][ct] = mfma16(pfrag, bV[kk][ct], oacc[qt2][ct]);
      }
    }

    if (kb < 15) __syncthreads();  // drains stage vmcnt; next buffer ready
  }

  // ---- epilogue: unnormalized partial O + (m, l) ----
#pragma unroll
  for (int qt2 = 0; qt2 < 2; ++qt2)
#pragma unroll
    for (int ct = 0; ct < 4; ++ct)
#pragma unroll
      for (int r = 0; r < 4; ++r) {
        const int q = q0 + qt2 * 16 + lhi * 4 + r;
        const int c = ct * 16 + lrow;
        Opart[(((size_t)b * NPIX + q) * 4 + ks) * 64 + c] = oacc[qt2][ct][r];
      }
  if (lhi < 2) {
    const int q = q0 + lhi * 16 + lrow;
    const size_t base = (((size_t)b * NPIX + q) * 4 + ks) * 2;
    mlbuf[base]     = m_run[lhi];
    mlbuf[base + 1] = l_run[lhi];
  }
}

// ========================= stage 3: merge + wout + BN =======================
// grid (128, 4): 32 pixels/block.
__global__ __launch_bounds__(256) void merge_out(
    const float* __restrict__ Opart, const float* __restrict__ mlbuf,
    const float* __restrict__ ww,  const float* __restrict__ wb,
    const float* __restrict__ wg,  const float* __restrict__ wbt,
    const float* __restrict__ wm,  const float* __restrict__ wvv,
    float* __restrict__ out)
{
  __shared__ float wlds[128][64];   // folded wout
  __shared__ float bfw[128];
  __shared__ float mrg[32][68];     // merged O, pitch 68

  const int tid = threadIdx.x;
  const int b   = blockIdx.y;
  const int n0  = blockIdx.x * 32;

  for (int idx = tid; idx < 128 * 64; idx += 256) {
    const int o = idx >> 6, c = idx & 63;
    const float sc = wg[o] * rsqrtf(wvv[o] + EPS);
    wlds[o][c] = ww[o * 64 + c] * sc;
    if (c == 0) bfw[o] = wb[o] * sc + wbt[o] - wm[o] * sc;
  }

  // ---- merge K-split partials ----
  {
    const int px = tid & 31;
    const int cg = tid >> 5;         // 8 channel-groups of 8
    const int q  = n0 + px;
    const size_t sb = ((size_t)b * NPIX + q) * 4;
    float mk[4], lk[4];
#pragma unroll
    for (int ks = 0; ks < 4; ++ks) {
      mk[ks] = mlbuf[(sb + ks) * 2];
      lk[ks] = mlbuf[(sb + ks) * 2 + 1];
    }
    const float M = fmaxf(fmaxf(mk[0], mk[1]), fmaxf(mk[2], mk[3]));
    float al[4]; float den = 0.f;
#pragma unroll
    for (int ks = 0; ks < 4; ++ks) { al[ks] = __expf(mk[ks] - M); den += al[ks] * lk[ks]; }
    const float inv = 1.f / den;
#pragma unroll
    for (int ks = 0; ks < 4; ++ks) al[ks] *= inv;

    f32x4 r0 = fzero4(), r1 = fzero4();
#pragma unroll
    for (int ks = 0; ks < 4; ++ks) {
      const f32x4 p0 = *(const f32x4*)(Opart + (sb + ks) * 64 + cg * 8);
      const f32x4 p1 = *(const f32x4*)(Opart + (sb + ks) * 64 + cg * 8 + 4);
      r0 += p0 * al[ks];
      r1 += p1 * al[ks];
    }
    *(f32x4*)&mrg[px][cg * 8]     = r0;
    *(f32x4*)&mrg[px][cg * 8 + 4] = r1;
  }
  __syncthreads();

  // ---- wout GEMM: thread owns (pixel, 16 out-channels) ----
  const int px = tid & 31;
  const int oh = tid >> 5;
  float acc[16];
#pragma unroll
  for (int j = 0; j < 16; ++j) acc[j] = 0.f;

#pragma unroll 4
  for (int c0 = 0; c0 < 64; c0 += 4) {
    const f32x4 m4 = *(const f32x4*)&mrg[px][c0];
#pragma unroll
    for (int j = 0; j < 16; ++j) {
      const f32x4 w4 = *(const f32x4*)&wlds[oh * 16 + j][c0];
      acc[j] += w4[0] * m4[0] + w4[1] * m4[1] + w4[2] * m4[2] + w4[3] * m4[3];
    }
  }
#pragma unroll
  for (int j = 0; j < 16; ++j) {
    const int o = oh * 16 + j;
    out[((size_t)b * 256 + o) * NPIX + n0 + px] = acc[j] + bfw[o];
  }
}

// ============================== launcher ====================================
extern "C" void kernel_launch(void* const* d_in, const int* in_sizes, int n_in,
                              void* d_out, int out_size, void* d_ws, size_t ws_size,
                              hipStream_t stream) {
  (void)in_sizes; (void)n_in; (void)out_size; (void)ws_size;
  const float* x1  = (const float*)d_in[0];
  const float* x2  = (const float*)d_in[1];
  const float* tw  = (const float*)d_in[2];
  const float* tb  = (const float*)d_in[3];
  const float* tg  = (const float*)d_in[4];
  const float* tbt = (const float*)d_in[5];
  const float* tm  = (const float*)d_in[6];
  const float* tv  = (const float*)d_in[7];
  const float* pw  = (const float*)d_in[8];
  const float* pb  = (const float*)d_in[9];
  const float* pg  = (const float*)d_in[10];
  const float* pbt = (const float*)d_in[11];
  const float* pm  = (const float*)d_in[12];
  const float* pv  = (const float*)d_in[13];
  const float* gw  = (const float*)d_in[14];
  const float* gb  = (const float*)d_in[15];
  const float* gg  = (const float*)d_in[16];
  const float* gbt = (const float*)d_in[17];
  const float* gmn = (const float*)d_in[18];
  const float* gv  = (const float*)d_in[19];
  const float* ww  = (const float*)d_in[20];
  const float* wb  = (const float*)d_in[21];
  const float* wg  = (const float*)d_in[22];
  const float* wbt = (const float*)d_in[23];
  const float* wm  = (const float*)d_in[24];
  const float* wv  = (const float*)d_in[25];

  float* out = (float*)d_out;
  char*  ws  = (char*)d_ws;
  bf16_t* thetaT_h = (bf16_t*)(ws);
  bf16_t* thetaT_l = (bf16_t*)(ws + (size_t)(2)  * 1048576);
  bf16_t* phiT_h   = (bf16_t*)(ws + (size_t)(4)  * 1048576);
  bf16_t* phiT_l   = (bf16_t*)(ws + (size_t)(6)  * 1048576);
  bf16_t* g_cm     = (bf16_t*)(ws + (size_t)(8)  * 1048576);
  float*  Opart    = (float*) (ws + (size_t)(10) * 1048576);
  float*  mlbuf    = (float*) (ws + (size_t)(26) * 1048576);

  dim3 gp(128, 4);
  proj_theta<<<gp, 256, 0, stream>>>(x1, tw, tb, tg, tbt, tm, tv,
                                     thetaT_h, thetaT_l, out);
  proj_phi<<<gp, 256, 0, stream>>>(x2, pw, pb, pg, pbt, pm, pv,
                                   phiT_h, phiT_l);
  proj_g<<<gp, 256, 0, stream>>>(x2, gw, gb, gg, gbt, gmn, gv, g_cm);
  flash_attn<<<512, 256, 0, stream>>>(thetaT_h, thetaT_l, phiT_h, phiT_l,
                                      g_cm, Opart, mlbuf);
  merge_out<<<gp, 256, 0, stream>>>(Opart, mlbuf, ww, wb, wg, wbt, wm, wv, out);
}